// Round 1
// baseline (121.805 us; speedup 1.0000x reference)
//
#include <hip/hip_runtime.h>

namespace {

constexpr int H = 512;
constexpr int W = 512;
constexpr float EPSV  = 1e-6f;
constexpr float NMAXV = 0.85f;

// Compute 4-neighbor average and squared-gradient for 4 contiguous pixels
// (edge-clamped, matching jnp.pad mode='edge').
__device__ __forceinline__ void stencil4(const float* __restrict__ a, size_t pb,
                                         int y, int x0, const float c[4],
                                         float avg[4], float gsq[4])
{
    const int ym = (y > 0) ? y - 1 : 0;
    const int yp = (y < H - 1) ? y + 1 : H - 1;
    const float4 upv = *(const float4*)(a + pb + (size_t)ym * W + x0);
    const float4 dnv = *(const float4*)(a + pb + (size_t)yp * W + x0);
    const float up[4] = {upv.x, upv.y, upv.z, upv.w};
    const float dn[4] = {dnv.x, dnv.y, dnv.z, dnv.w};
    float lf[4], rt[4];
    lf[0] = (x0 == 0)     ? c[0] : a[pb + (size_t)y * W + (x0 - 1)];
    lf[1] = c[0]; lf[2] = c[1]; lf[3] = c[2];
    rt[0] = c[1]; rt[1] = c[2]; rt[2] = c[3];
    rt[3] = (x0 + 4 >= W) ? c[3] : a[pb + (size_t)y * W + (x0 + 4)];
#pragma unroll
    for (int j = 0; j < 4; ++j) {
        avg[j] = 0.25f * (up[j] + dn[j] + lf[j] + rt[j]);
        const float gx = 0.5f * (rt[j] - lf[j]);
        const float gy = 0.5f * (dn[j] - up[j]);
        gsq[j] = gx * gx + gy * gy;
    }
}

__global__ __launch_bounds__(256) void lef_kernel(
    const float* __restrict__ u,  const float* __restrict__ v,
    const float* __restrict__ u0, const float* __restrict__ p,
    const float* __restrict__ q,
    const float* __restrict__ s_alpha, const float* __restrict__ s_beta,
    const float* __restrict__ s_kappa, const float* __restrict__ s_lam,
    const float* __restrict__ s_omega,
    float* __restrict__ out_u, float* __restrict__ out_v,
    int nplanes)
{
    const float alpha  = s_alpha[0];
    const float beta   = s_beta[0];
    const float kappa  = s_kappa[0];
    const float lam    = s_lam[0];
    const float omega  = s_omega[0];
    const float inv_k2 = 1.0f / (kappa * kappa);

    const int tid   = blockIdx.x * blockDim.x + threadIdx.x;
    const int wq    = W / 4;
    const int total = nplanes * H * wq;
    if (tid >= total) return;

    const int xq    = tid % wq;
    const int rest  = tid / wq;
    const int y     = rest % H;
    const int plane = rest / H;
    const int x0    = xq * 4;
    const size_t pb   = (size_t)plane * H * W;
    const size_t base = pb + (size_t)y * W + x0;

    const float4 uc4  = *(const float4*)(u  + base);
    const float4 vc4  = *(const float4*)(v  + base);
    const float4 u04  = *(const float4*)(u0 + base);
    const float4 p4   = *(const float4*)(p  + base);
    const float4 q4   = *(const float4*)(q  + base);
    const float uc[4]  = {uc4.x, uc4.y, uc4.z, uc4.w};
    const float vc[4]  = {vc4.x, vc4.y, vc4.z, vc4.w};
    const float u0a[4] = {u04.x, u04.y, u04.z, u04.w};
    const float pa[4]  = {p4.x,  p4.y,  p4.z,  p4.w};
    const float qa[4]  = {q4.x,  q4.y,  q4.z,  q4.w};

    float uavg[4], ugsq[4], vavg[4], vgsq[4];
    stencil4(u, pb, y, x0, uc, uavg, ugsq);
    stencil4(v, pb, y, x0, vc, vavg, vgsq);

    float ou[4], ov[4];
#pragma unroll
    for (int j = 0; j < 4; ++j) {
        const float u_safe = fmaxf(uc[j], EPSV);
        const float v_safe = fmaxf(vc[j], EPSV);
        const float N_u = fminf(pa[j] * powf(v_safe, alpha), NMAXV);
        const float N_v = fminf(qa[j] * powf(u_safe, beta),  NMAXV);
        const float ce_u = expf(-ugsq[j] * inv_k2);
        const float ce_v = expf(-vgsq[j] * inv_k2);
        const float u_sm = uavg[j] + N_u * 0.25f;
        const float v_sm = vavg[j] + N_v * 0.25f;
        const float u_cand = ce_u * u_sm + (1.0f - ce_u) * uc[j];
        const float v_cand = ce_v * v_sm + (1.0f - ce_v) * vc[j];
        ou[j] = (1.0f - omega) * uc[j] + omega * ((1.0f - lam) * u_cand + lam * u0a[j]);
        ov[j] = (1.0f - omega) * vc[j] + omega * ((1.0f - lam) * v_cand + lam * u0a[j]);
    }

    *(float4*)(out_u + base) = make_float4(ou[0], ou[1], ou[2], ou[3]);
    *(float4*)(out_v + base) = make_float4(ov[0], ov[1], ov[2], ov[3]);
}

} // namespace

extern "C" void kernel_launch(void* const* d_in, const int* in_sizes, int n_in,
                              void* d_out, int out_size, void* d_ws, size_t ws_size,
                              hipStream_t stream)
{
    const float* u  = (const float*)d_in[0];
    const float* v  = (const float*)d_in[1];
    const float* u0 = (const float*)d_in[2];
    const float* p  = (const float*)d_in[3];
    const float* q  = (const float*)d_in[4];
    const float* s_alpha = (const float*)d_in[5];
    const float* s_beta  = (const float*)d_in[6];
    const float* s_kappa = (const float*)d_in[7];
    const float* s_lam   = (const float*)d_in[8];
    const float* s_omega = (const float*)d_in[9];

    const int n_elems = in_sizes[0];          // 16*3*512*512
    const int nplanes = n_elems / (H * W);    // 48
    float* out_u = (float*)d_out;
    float* out_v = (float*)d_out + n_elems;

    const int threads = nplanes * H * (W / 4);
    const int block = 256;
    const int grid  = (threads + block - 1) / block;

    lef_kernel<<<grid, block, 0, stream>>>(u, v, u0, p, q,
                                           s_alpha, s_beta, s_kappa, s_lam, s_omega,
                                           out_u, out_v, nplanes);
}

// Round 2
// 71.044 us; speedup vs baseline: 1.7145x; 1.7145x over previous
//
#include <hip/hip_runtime.h>

namespace {

constexpr int H = 512;
constexpr int W = 512;
constexpr float EPSV   = 1e-6f;
constexpr float NMAXV  = 0.85f;
constexpr float LOG2E  = 1.4426950408889634f;

// Hardware transcendentals: v_exp_f32 computes 2^x, v_log_f32 computes log2(x).
__device__ __forceinline__ float fexp2(float x) {
#if __has_builtin(__builtin_amdgcn_exp2f)
    return __builtin_amdgcn_exp2f(x);
#else
    return exp2f(x);
#endif
}
__device__ __forceinline__ float flog2(float x) {
#if __has_builtin(__builtin_amdgcn_logf)
    return __builtin_amdgcn_logf(x);
#else
    return log2f(x);
#endif
}

// 4-neighbor average and squared-gradient for 4 contiguous pixels
// (edge-clamped, matching jnp.pad mode='edge').
__device__ __forceinline__ void stencil4(const float* __restrict__ a, size_t pb,
                                         int y, int x0, const float c[4],
                                         float avg[4], float gsq[4])
{
    const int ym = (y > 0) ? y - 1 : 0;
    const int yp = (y < H - 1) ? y + 1 : H - 1;
    const float4 upv = *(const float4*)(a + pb + (size_t)ym * W + x0);
    const float4 dnv = *(const float4*)(a + pb + (size_t)yp * W + x0);
    const float up[4] = {upv.x, upv.y, upv.z, upv.w};
    const float dn[4] = {dnv.x, dnv.y, dnv.z, dnv.w};
    float lf[4], rt[4];
    lf[0] = (x0 == 0)     ? c[0] : a[pb + (size_t)y * W + (x0 - 1)];
    lf[1] = c[0]; lf[2] = c[1]; lf[3] = c[2];
    rt[0] = c[1]; rt[1] = c[2]; rt[2] = c[3];
    rt[3] = (x0 + 4 >= W) ? c[3] : a[pb + (size_t)y * W + (x0 + 4)];
#pragma unroll
    for (int j = 0; j < 4; ++j) {
        avg[j] = 0.25f * (up[j] + dn[j] + lf[j] + rt[j]);
        const float gx = 0.5f * (rt[j] - lf[j]);
        const float gy = 0.5f * (dn[j] - up[j]);
        gsq[j] = gx * gx + gy * gy;
    }
}

__global__ __launch_bounds__(256) void lef_kernel(
    const float* __restrict__ u,  const float* __restrict__ v,
    const float* __restrict__ u0, const float* __restrict__ p,
    const float* __restrict__ q,
    const float* __restrict__ s_alpha, const float* __restrict__ s_beta,
    const float* __restrict__ s_kappa, const float* __restrict__ s_lam,
    const float* __restrict__ s_omega,
    float* __restrict__ out_u, float* __restrict__ out_v,
    int nplanes)
{
    const float alpha = s_alpha[0];
    const float beta  = s_beta[0];
    const float kappa = s_kappa[0];
    const float lam   = s_lam[0];
    const float omega = s_omega[0];
    // c_edge = exp(-g/k^2) = 2^(-g * inv_k2 * log2(e))
    const float nk2 = (1.0f / (kappa * kappa)) * LOG2E;
    // u_new = (1-w)u + w[(1-l)cand + l*u0]  ->  cw*u-part folded:
    const float w_cand = omega * (1.0f - lam);   // coeff of cand
    const float w_u0   = omega * lam;            // coeff of u0
    const float w_self = 1.0f - omega;           // coeff of u (plus cand's own u term)

    const int tid   = blockIdx.x * blockDim.x + threadIdx.x;
    const int wq    = W / 4;
    const int total = nplanes * H * wq;
    if (tid >= total) return;

    const int xq    = tid % wq;
    const int rest  = tid / wq;
    const int y     = rest % H;
    const int plane = rest / H;
    const int x0    = xq * 4;
    const size_t pb   = (size_t)plane * H * W;
    const size_t base = pb + (size_t)y * W + x0;

    const float4 uc4  = *(const float4*)(u  + base);
    const float4 vc4  = *(const float4*)(v  + base);
    const float4 u04  = *(const float4*)(u0 + base);
    const float4 p4   = *(const float4*)(p  + base);
    const float4 q4   = *(const float4*)(q  + base);
    const float uc[4]  = {uc4.x, uc4.y, uc4.z, uc4.w};
    const float vc[4]  = {vc4.x, vc4.y, vc4.z, vc4.w};
    const float u0a[4] = {u04.x, u04.y, u04.z, u04.w};
    const float pa[4]  = {p4.x,  p4.y,  p4.z,  p4.w};
    const float qa[4]  = {q4.x,  q4.y,  q4.z,  q4.w};

    float uavg[4], ugsq[4], vavg[4], vgsq[4];
    stencil4(u, pb, y, x0, uc, uavg, ugsq);
    stencil4(v, pb, y, x0, vc, vavg, vgsq);

    float ou[4], ov[4];
#pragma unroll
    for (int j = 0; j < 4; ++j) {
        const float u_safe = fmaxf(uc[j], EPSV);
        const float v_safe = fmaxf(vc[j], EPSV);
        // pow via hw log2/exp2 (args strictly positive)
        const float N_u = fminf(pa[j] * fexp2(alpha * flog2(v_safe)), NMAXV);
        const float N_v = fminf(qa[j] * fexp2(beta  * flog2(u_safe)), NMAXV);
        const float ce_u = fexp2(-ugsq[j] * nk2);
        const float ce_v = fexp2(-vgsq[j] * nk2);
        const float u_sm = uavg[j] + N_u * 0.25f;
        const float v_sm = vavg[j] + N_v * 0.25f;
        const float u_cand = ce_u * u_sm + (1.0f - ce_u) * uc[j];
        const float v_cand = ce_v * v_sm + (1.0f - ce_v) * vc[j];
        ou[j] = w_self * uc[j] + w_cand * u_cand + w_u0 * u0a[j];
        ov[j] = w_self * vc[j] + w_cand * v_cand + w_u0 * u0a[j];
    }

    *(float4*)(out_u + base) = make_float4(ou[0], ou[1], ou[2], ou[3]);
    *(float4*)(out_v + base) = make_float4(ov[0], ov[1], ov[2], ov[3]);
}

} // namespace

extern "C" void kernel_launch(void* const* d_in, const int* in_sizes, int n_in,
                              void* d_out, int out_size, void* d_ws, size_t ws_size,
                              hipStream_t stream)
{
    const float* u  = (const float*)d_in[0];
    const float* v  = (const float*)d_in[1];
    const float* u0 = (const float*)d_in[2];
    const float* p  = (const float*)d_in[3];
    const float* q  = (const float*)d_in[4];
    const float* s_alpha = (const float*)d_in[5];
    const float* s_beta  = (const float*)d_in[6];
    const float* s_kappa = (const float*)d_in[7];
    const float* s_lam   = (const float*)d_in[8];
    const float* s_omega = (const float*)d_in[9];

    const int n_elems = in_sizes[0];          // 16*3*512*512
    const int nplanes = n_elems / (H * W);    // 48
    float* out_u = (float*)d_out;
    float* out_v = (float*)d_out + n_elems;

    const int threads = nplanes * H * (W / 4);
    const int block = 256;
    const int grid  = (threads + block - 1) / block;

    lef_kernel<<<grid, block, 0, stream>>>(u, v, u0, p, q,
                                           s_alpha, s_beta, s_kappa, s_lam, s_omega,
                                           out_u, out_v, nplanes);
}

// Round 3
// 61.852 us; speedup vs baseline: 1.9693x; 1.1486x over previous
//
#include <hip/hip_runtime.h>

namespace {

constexpr int H = 512;
constexpr int W = 512;
constexpr float EPSV   = 1e-6f;
constexpr float NMAXV  = 0.85f;
constexpr float LOG2E  = 1.4426950408889634f;

typedef float f4v __attribute__((ext_vector_type(4)));

__device__ __forceinline__ float fexp2(float x) {
#if __has_builtin(__builtin_amdgcn_exp2f)
    return __builtin_amdgcn_exp2f(x);
#else
    return exp2f(x);
#endif
}
__device__ __forceinline__ float flog2(float x) {
#if __has_builtin(__builtin_amdgcn_logf)
    return __builtin_amdgcn_logf(x);
#else
    return log2f(x);
#endif
}

__device__ __forceinline__ void unpack(const float4 v, float o[4]) {
    o[0] = v.x; o[1] = v.y; o[2] = v.z; o[3] = v.w;
}

// Stencil for one row of 4 pixels given neighbor rows + resolved edge scalars.
__device__ __forceinline__ void stencil_row(const float up[4], const float dn[4],
                                            const float c[4], float lf0, float rt3,
                                            float avg[4], float gsq[4])
{
    const float lf[4] = {lf0, c[0], c[1], c[2]};
    const float rt[4] = {c[1], c[2], c[3], rt3};
#pragma unroll
    for (int j = 0; j < 4; ++j) {
        avg[j] = 0.25f * (up[j] + dn[j] + lf[j] + rt[j]);
        const float gx = 0.5f * (rt[j] - lf[j]);
        const float gy = 0.5f * (dn[j] - up[j]);
        gsq[j] = gx * gx + gy * gy;
    }
}

__global__ __launch_bounds__(256) void lef_kernel(
    const float* __restrict__ u,  const float* __restrict__ v,
    const float* __restrict__ u0, const float* __restrict__ p,
    const float* __restrict__ q,
    const float* __restrict__ s_alpha, const float* __restrict__ s_beta,
    const float* __restrict__ s_kappa, const float* __restrict__ s_lam,
    const float* __restrict__ s_omega,
    float* __restrict__ out_u, float* __restrict__ out_v)
{
    const float alpha = s_alpha[0];
    const float beta  = s_beta[0];
    const float kappa = s_kappa[0];
    const float lam   = s_lam[0];
    const float omega = s_omega[0];
    const float nk2    = (1.0f / (kappa * kappa)) * LOG2E;   // c_edge = 2^(-g*nk2)
    const float w_cand = omega * (1.0f - lam);
    const float w_u0   = omega * lam;
    const float w_self = 1.0f - omega;

    // thread -> (plane, row-pair, x-quad); grid is exact.
    const int tid   = blockIdx.x * 256 + threadIdx.x;
    const int xq    = tid & 127;          // W/4 = 128
    const int rest  = tid >> 7;
    const int y0    = (rest & 255) << 1;  // H/2 = 256 row-pairs
    const int plane = rest >> 8;
    const int x0    = xq << 2;
    const int y1    = y0 + 1;
    const int ym    = (y0 > 0) ? y0 - 1 : 0;
    const int y2    = (y1 < H - 1) ? y1 + 1 : H - 1;

    const size_t pb = (size_t)plane * (H * W);
    const size_t rm = pb + (size_t)ym * W + x0;
    const size_t r0 = pb + (size_t)y0 * W + x0;
    const size_t r1 = pb + (size_t)y1 * W + x0;
    const size_t r2 = pb + (size_t)y2 * W + x0;

    // ---- loads (issue everything up front for max MLP) ----
    float u_m[4], u_0[4], u_1[4], u_2[4];
    float v_m[4], v_0[4], v_1[4], v_2[4];
    float u0_0[4], u0_1[4], p_0[4], p_1[4], q_0[4], q_1[4];
    unpack(*(const float4*)(u + rm), u_m);
    unpack(*(const float4*)(u + r0), u_0);
    unpack(*(const float4*)(u + r1), u_1);
    unpack(*(const float4*)(u + r2), u_2);
    unpack(*(const float4*)(v + rm), v_m);
    unpack(*(const float4*)(v + r0), v_0);
    unpack(*(const float4*)(v + r1), v_1);
    unpack(*(const float4*)(v + r2), v_2);
    unpack(*(const float4*)(u0 + r0), u0_0);
    unpack(*(const float4*)(u0 + r1), u0_1);
    unpack(*(const float4*)(p + r0), p_0);
    unpack(*(const float4*)(p + r1), p_1);
    unpack(*(const float4*)(q + r0), q_0);
    unpack(*(const float4*)(q + r1), q_1);

    const bool le = (x0 == 0);
    const bool re = (x0 == W - 4);
    const float ulf0 = le ? u_0[0] : u[r0 - 1];
    const float ulf1 = le ? u_1[0] : u[r1 - 1];
    const float vlf0 = le ? v_0[0] : v[r0 - 1];
    const float vlf1 = le ? v_1[0] : v[r1 - 1];
    const float urt0 = re ? u_0[3] : u[r0 + 4];
    const float urt1 = re ? u_1[3] : u[r1 + 4];
    const float vrt0 = re ? v_0[3] : v[r0 + 4];
    const float vrt1 = re ? v_1[3] : v[r1 + 4];

    // ---- stencil ----
    float uavg0[4], ugsq0[4], uavg1[4], ugsq1[4];
    float vavg0[4], vgsq0[4], vavg1[4], vgsq1[4];
    stencil_row(u_m, u_1, u_0, ulf0, urt0, uavg0, ugsq0);
    stencil_row(u_0, u_2, u_1, ulf1, urt1, uavg1, ugsq1);
    stencil_row(v_m, v_1, v_0, vlf0, vrt0, vavg0, vgsq0);
    stencil_row(v_0, v_2, v_1, vlf1, vrt1, vavg1, vgsq1);

    // ---- pointwise math, both rows ----
    f4v ou0, ov0, ou1, ov1;
#pragma unroll
    for (int r = 0; r < 2; ++r) {
        const float* uc  = r ? u_1  : u_0;
        const float* vc  = r ? v_1  : v_0;
        const float* u0a = r ? u0_1 : u0_0;
        const float* pa  = r ? p_1  : p_0;
        const float* qa  = r ? q_1  : q_0;
        const float* ua  = r ? uavg1 : uavg0;
        const float* ug  = r ? ugsq1 : ugsq0;
        const float* va  = r ? vavg1 : vavg0;
        const float* vg  = r ? vgsq1 : vgsq0;
        f4v ou, ov;
#pragma unroll
        for (int j = 0; j < 4; ++j) {
            const float u_safe = fmaxf(uc[j], EPSV);
            const float v_safe = fmaxf(vc[j], EPSV);
            const float N_u = fminf(pa[j] * fexp2(alpha * flog2(v_safe)), NMAXV);
            const float N_v = fminf(qa[j] * fexp2(beta  * flog2(u_safe)), NMAXV);
            const float ce_u = fexp2(-ug[j] * nk2);
            const float ce_v = fexp2(-vg[j] * nk2);
            const float u_sm = ua[j] + N_u * 0.25f;
            const float v_sm = va[j] + N_v * 0.25f;
            const float u_cand = ce_u * u_sm + (1.0f - ce_u) * uc[j];
            const float v_cand = ce_v * v_sm + (1.0f - ce_v) * vc[j];
            ou[j] = w_self * uc[j] + w_cand * u_cand + w_u0 * u0a[j];
            ov[j] = w_self * vc[j] + w_cand * v_cand + w_u0 * u0a[j];
        }
        if (r) { ou1 = ou; ov1 = ov; } else { ou0 = ou; ov0 = ov; }
    }

    // ---- non-temporal stores (keep outputs from evicting L2/L3 input lines) ----
    __builtin_nontemporal_store(ou0, (f4v*)(out_u + r0));
    __builtin_nontemporal_store(ou1, (f4v*)(out_u + r1));
    __builtin_nontemporal_store(ov0, (f4v*)(out_v + r0));
    __builtin_nontemporal_store(ov1, (f4v*)(out_v + r1));
}

} // namespace

extern "C" void kernel_launch(void* const* d_in, const int* in_sizes, int n_in,
                              void* d_out, int out_size, void* d_ws, size_t ws_size,
                              hipStream_t stream)
{
    const float* u  = (const float*)d_in[0];
    const float* v  = (const float*)d_in[1];
    const float* u0 = (const float*)d_in[2];
    const float* p  = (const float*)d_in[3];
    const float* q  = (const float*)d_in[4];
    const float* s_alpha = (const float*)d_in[5];
    const float* s_beta  = (const float*)d_in[6];
    const float* s_kappa = (const float*)d_in[7];
    const float* s_lam   = (const float*)d_in[8];
    const float* s_omega = (const float*)d_in[9];

    const int n_elems = in_sizes[0];          // 16*3*512*512
    const int nplanes = n_elems / (H * W);    // 48
    float* out_u = (float*)d_out;
    float* out_v = (float*)d_out + n_elems;

    const int threads = nplanes * (H / 2) * (W / 4);   // exact
    const int block = 256;
    const int grid  = threads / block;

    lef_kernel<<<grid, block, 0, stream>>>(u, v, u0, p, q,
                                           s_alpha, s_beta, s_kappa, s_lam, s_omega,
                                           out_u, out_v);
}

// Round 4
// 60.864 us; speedup vs baseline: 2.0013x; 1.0162x over previous
//
#include <hip/hip_runtime.h>

namespace {

constexpr int H = 512;
constexpr int W = 512;
constexpr float EPSV   = 1e-6f;
constexpr float NMAXV  = 0.85f;
constexpr float LOG2E  = 1.4426950408889634f;

typedef float f4v __attribute__((ext_vector_type(4)));

__device__ __forceinline__ float fexp2(float x) {
#if __has_builtin(__builtin_amdgcn_exp2f)
    return __builtin_amdgcn_exp2f(x);
#else
    return exp2f(x);
#endif
}
__device__ __forceinline__ float flog2(float x) {
#if __has_builtin(__builtin_amdgcn_logf)
    return __builtin_amdgcn_logf(x);
#else
    return log2f(x);
#endif
}

__device__ __forceinline__ void unpack(const float4 v, float o[4]) {
    o[0] = v.x; o[1] = v.y; o[2] = v.z; o[3] = v.w;
}

__global__ __launch_bounds__(256) void lef_kernel(
    const float* __restrict__ u,  const float* __restrict__ v,
    const float* __restrict__ u0, const float* __restrict__ p,
    const float* __restrict__ q,
    const float* __restrict__ s_alpha, const float* __restrict__ s_beta,
    const float* __restrict__ s_kappa, const float* __restrict__ s_lam,
    const float* __restrict__ s_omega,
    float* __restrict__ out_u, float* __restrict__ out_v)
{
    const float alpha = s_alpha[0];
    const float beta  = s_beta[0];
    const float kappa = s_kappa[0];
    const float lam   = s_lam[0];
    const float omega = s_omega[0];
    const float nk2    = (1.0f / (kappa * kappa)) * LOG2E;   // c_edge = 2^(-g*nk2)
    const float w_cand = omega * (1.0f - lam);
    const float w_u0   = omega * lam;
    const float w_self = 1.0f - omega;

    // thread -> (plane, 4-row block, x-quad); grid exact; 32-bit offsets.
    const int tid   = blockIdx.x * 256 + threadIdx.x;
    const int xq    = tid & 127;           // W/4 = 128
    const int rest  = tid >> 7;
    const int yb    = rest & 127;          // H/4 = 128 row-blocks
    const int plane = rest >> 7;
    const int x0    = xq << 2;
    const int y0    = yb << 2;
    const int pb    = plane * (H * W);

    // 6 source rows: y0-1 (clamped), y0..y3, y0+4 (clamped)
    int ro[6];
    ro[0] = pb + ((y0 > 0) ? y0 - 1 : 0) * W + x0;
    ro[1] = pb + y0 * W + x0;
    ro[2] = ro[1] + W;
    ro[3] = ro[2] + W;
    ro[4] = ro[3] + W;
    ro[5] = pb + ((y0 + 4 < H) ? y0 + 4 : H - 1) * W + x0;

    // ---- vector loads up front (max MLP) ----
    float ur[6][4], vr[6][4];
#pragma unroll
    for (int i = 0; i < 6; ++i) unpack(*(const float4*)(u + ro[i]), ur[i]);
#pragma unroll
    for (int i = 0; i < 6; ++i) unpack(*(const float4*)(v + ro[i]), vr[i]);

    float u0r[4][4], pr[4][4], qr[4][4];
#pragma unroll
    for (int i = 0; i < 4; ++i) unpack(*(const float4*)(u0 + ro[i + 1]), u0r[i]);
#pragma unroll
    for (int i = 0; i < 4; ++i) unpack(*(const float4*)(p + ro[i + 1]), pr[i]);
#pragma unroll
    for (int i = 0; i < 4; ++i) unpack(*(const float4*)(q + ro[i + 1]), qr[i]);

    // ---- edge scalars for the 4 center rows ----
    const bool le = (x0 == 0);
    const bool re = (x0 == W - 4);
    float ulf[4], urt[4], vlf[4], vrt[4];
#pragma unroll
    for (int i = 0; i < 4; ++i) {
        const int rc = ro[i + 1];
        ulf[i] = le ? ur[i + 1][0] : u[rc - 1];
        urt[i] = re ? ur[i + 1][3] : u[rc + 4];
        vlf[i] = le ? vr[i + 1][0] : v[rc - 1];
        vrt[i] = re ? vr[i + 1][3] : v[rc + 4];
    }

    // ---- per-row stencil + pointwise, store as we go ----
#pragma unroll
    for (int i = 0; i < 4; ++i) {
        const float* uu = ur[i];       // up
        const float* uc = ur[i + 1];   // center
        const float* ud = ur[i + 2];   // down
        const float* vu = vr[i];
        const float* vc = vr[i + 1];
        const float* vd = vr[i + 2];
        const float ul[4] = {ulf[i], uc[0], uc[1], uc[2]};
        const float ur_[4] = {uc[1], uc[2], uc[3], urt[i]};
        const float vl[4] = {vlf[i], vc[0], vc[1], vc[2]};
        const float vr_[4] = {vc[1], vc[2], vc[3], vrt[i]};

        f4v ou, ov;
#pragma unroll
        for (int j = 0; j < 4; ++j) {
            const float uavg = 0.25f * (uu[j] + ud[j] + ul[j] + ur_[j]);
            const float ugx = 0.5f * (ur_[j] - ul[j]);
            const float ugy = 0.5f * (ud[j] - uu[j]);
            const float ugsq = ugx * ugx + ugy * ugy;
            const float vavg = 0.25f * (vu[j] + vd[j] + vl[j] + vr_[j]);
            const float vgx = 0.5f * (vr_[j] - vl[j]);
            const float vgy = 0.5f * (vd[j] - vu[j]);
            const float vgsq = vgx * vgx + vgy * vgy;

            const float u_safe = fmaxf(uc[j], EPSV);
            const float v_safe = fmaxf(vc[j], EPSV);
            const float N_u = fminf(pr[i][j] * fexp2(alpha * flog2(v_safe)), NMAXV);
            const float N_v = fminf(qr[i][j] * fexp2(beta  * flog2(u_safe)), NMAXV);
            const float ce_u = fexp2(-ugsq * nk2);
            const float ce_v = fexp2(-vgsq * nk2);
            const float u_sm = uavg + N_u * 0.25f;
            const float v_sm = vavg + N_v * 0.25f;
            const float u_cand = ce_u * u_sm + (1.0f - ce_u) * uc[j];
            const float v_cand = ce_v * v_sm + (1.0f - ce_v) * vc[j];
            ou[j] = w_self * uc[j] + w_cand * u_cand + w_u0 * u0r[i][j];
            ov[j] = w_self * vc[j] + w_cand * v_cand + w_u0 * u0r[i][j];
        }
        __builtin_nontemporal_store(ou, (f4v*)(out_u + ro[i + 1]));
        __builtin_nontemporal_store(ov, (f4v*)(out_v + ro[i + 1]));
    }
}

} // namespace

extern "C" void kernel_launch(void* const* d_in, const int* in_sizes, int n_in,
                              void* d_out, int out_size, void* d_ws, size_t ws_size,
                              hipStream_t stream)
{
    const float* u  = (const float*)d_in[0];
    const float* v  = (const float*)d_in[1];
    const float* u0 = (const float*)d_in[2];
    const float* p  = (const float*)d_in[3];
    const float* q  = (const float*)d_in[4];
    const float* s_alpha = (const float*)d_in[5];
    const float* s_beta  = (const float*)d_in[6];
    const float* s_kappa = (const float*)d_in[7];
    const float* s_lam   = (const float*)d_in[8];
    const float* s_omega = (const float*)d_in[9];

    const int n_elems = in_sizes[0];          // 16*3*512*512
    const int nplanes = n_elems / (H * W);    // 48
    float* out_u = (float*)d_out;
    float* out_v = (float*)d_out + n_elems;

    const int threads = nplanes * (H / 4) * (W / 4);   // exact
    const int block = 256;
    const int grid  = threads / block;

    lef_kernel<<<grid, block, 0, stream>>>(u, v, u0, p, q,
                                           s_alpha, s_beta, s_kappa, s_lam, s_omega,
                                           out_u, out_v);
}